// Round 5
// baseline (48.047 us; speedup 1.0000x reference)
//
#include <hip/hip_runtime.h>
#include <math.h>

// MinusAttention: score(i,j) = (w.q_i - w.k_j + b)/sqrt(E), causal softmax, @V.
// Softmax cancels the per-row (w.q_i + b) constant -> weights depend only on keys:
//   out[i] = prefix_{j<=i}(e_j * v_j) / prefix_{j<=i}(e_j),  e_j = exp(-(w.k_j)/8).
// Single kernel, decoupled-lookback segmented scan (rocPRIM pattern):
//   block = 128 rows of one (b,h); publish block aggregate (fence + flag),
//   wave 0 polls <=15 predecessor flags lane-parallel, sums aggregates,
//   in-block downsweep from register-resident values.
// Grid (512 blocks x 256 thr) << residency capacity -> co-resident -> no deadlock.

#define B_   4
#define S_   2048
#define H_   8
#define E_   64
#define BH_  (B_ * H_)
#define RPW  32                  // rows per wave
#define WPB  4                   // waves per block
#define RPB  (RPW * WPB)         // 128 rows per block
#define NC_  (S_ / RPB)          // 16 chunks per (b,h)
#define NBLK (BH_ * NC_)         // 512 blocks
#define AST  96                  // aggregate row stride (floats): 384B = 3 full lines

__global__ __launch_bounds__(256) void k_fused(const float* __restrict__ keys,
                                               const float* __restrict__ values,
                                               const float* __restrict__ w,
                                               float* __restrict__ agg,
                                               int* __restrict__ flags,
                                               float* __restrict__ out) {
    const int blk  = blockIdx.x;
    const int bh   = blk / NC_, c = blk % NC_;
    const int b    = bh / H_,  h = bh % H_;
    const int wave = threadIdx.x >> 6, lane = threadIdx.x & 63;
    const int cf   = lane & 15;          // float4 col within 64-elem row
    const int rq   = lane >> 4;          // 4 rows per pass

    __shared__ float e_lds[WPB][RPW];
    __shared__ float wnum[WPB][E_];
    __shared__ float wden[WPB];
    __shared__ float gpn[E_];
    __shared__ float gpd;

    const size_t rowW = (size_t)b * S_ + (size_t)c * RPB + (size_t)wave * RPW;

    // ---- scores for this wave's 32 rows: e = exp(-(w.k)/8) ----
    const float4 w4 = reinterpret_cast<const float4*>(w)[cf];
    const float* kbase = keys + (rowW * H_ + h) * (size_t)E_;
    #pragma unroll
    for (int g = 0; g < RPW / 4; ++g) {
        const int r = g * 4 + rq;
        const float4 kv = *reinterpret_cast<const float4*>(
            kbase + (size_t)r * (H_ * E_) + cf * 4);
        float p = kv.x * w4.x + kv.y * w4.y + kv.z * w4.z + kv.w * w4.w;
        p += __shfl_xor(p, 1);
        p += __shfl_xor(p, 2);
        p += __shfl_xor(p, 4);
        p += __shfl_xor(p, 8);
        if (cf == 0) e_lds[wave][r] = __expf(-p * 0.125f);
    }

    // ---- values for this wave's rows -> registers (channel = lane) ----
    const float* vp = values + (rowW * H_ + h) * (size_t)E_ + lane;
    float v_r[RPW];
    #pragma unroll
    for (int j = 0; j < RPW; ++j) v_r[j] = vp[(size_t)j * (H_ * E_)];

    __syncthreads();

    // ---- per-wave partial sums ----
    float num = 0.f, den = 0.f;
    #pragma unroll
    for (int j = 0; j < RPW; ++j) {
        const float e = e_lds[wave][j];
        num = fmaf(e, v_r[j], num);
        den += e;
    }
    wnum[wave][lane] = num;
    if (lane == 0) wden[wave] = den;
    __syncthreads();

    if (wave == 0) {
        // ---- publish block aggregate ----
        const float bn = wnum[0][lane] + wnum[1][lane] + wnum[2][lane] + wnum[3][lane];
        float* arow = agg + (size_t)blk * AST;
        arow[lane] = bn;
        if (lane == 0) arow[E_] = wden[0] + wden[1] + wden[2] + wden[3];
        __threadfence();                       // aggregate visible before flag
        if (lane == 0) atomicExch(&flags[blk], 1);

        // ---- decoupled lookback: poll predecessors lane-parallel ----
        const int base = bh * NC_;
        if (lane < c) {
            while (atomicAdd(&flags[base + lane], 0) == 0)
                __builtin_amdgcn_s_sleep(4);
        }
        __threadfence();                       // acquire: see their aggregates
        float pn = 0.f, pd = 0.f;
        for (int cp = base; cp < blk; ++cp) {
            const float* prow = agg + (size_t)cp * AST;
            pn += prow[lane];                  // coalesced 256B, L2/L3-hot
            pd += prow[E_];
        }
        gpn[lane] = pn;
        if (lane == 0) gpd = pd;
    }
    __syncthreads();

    // ---- in-block exclusive prefix + downsweep from registers ----
    float pnum = gpn[lane], pden = gpd;
    for (int w2 = 0; w2 < wave; ++w2) {
        pnum += wnum[w2][lane];
        pden += wden[w2];
    }
    float* op = out + (rowW * H_ + h) * (size_t)E_ + lane;   // L == S
    #pragma unroll
    for (int j = 0; j < RPW; ++j) {
        const float e = e_lds[wave][j];
        pnum = fmaf(e, v_r[j], pnum);
        pden += e;
        op[(size_t)j * (H_ * E_)] = pnum * __builtin_amdgcn_rcpf(pden);
    }
}

extern "C" void kernel_launch(void* const* d_in, const int* in_sizes, int n_in,
                              void* d_out, int out_size, void* d_ws, size_t ws_size,
                              hipStream_t stream) {
    // inputs: 0=queries (UNUSED), 1=keys, 2=values, 3=w_score,
    //         4=b_score (cancels), 5=attn_mask (sentinel -> causal)
    const float* keys   = (const float*)d_in[1];
    const float* values = (const float*)d_in[2];
    const float* w      = (const float*)d_in[3];
    float* out = (float*)d_out;

    // workspace: agg[NBLK*AST] floats | flags[NBLK] ints
    float* agg   = (float*)d_ws;
    int*   flags = (int*)(agg + (size_t)NBLK * AST);

    hipMemsetAsync(flags, 0, NBLK * sizeof(int), stream);   // capturable node
    hipLaunchKernelGGL(k_fused, dim3(NBLK), dim3(256), 0, stream,
                       keys, values, w, agg, flags, out);
}

// Round 6
// 19.665 us; speedup vs baseline: 2.4433x; 2.4433x over previous
//
#include <hip/hip_runtime.h>
#include <math.h>

// MinusAttention: score(i,j) = (w.q_i - w.k_j + b)/sqrt(E), causal softmax, @V.
// Softmax cancels the per-row (w.q_i + b) constant -> weights depend only on keys:
//   out[i] = prefix_{j<=i}(e_j * v_j) / prefix_{j<=i}(e_j),  e_j = exp(-(w.k_j)/8).
// Two kernels (lookback/coop-sync measured slower: reg-state doesn't survive
// divergent global-comm regions -> spills):
//   K1: chunk (32 rows) scores + chunk partial sums. float4 loads, LDS reduce.
//   K2: wave-strided prefix over predecessor chunks + per-wave downsweep + out.
// 2048 blocks x 256 threads each -> 8 blocks/CU, 32 waves/CU.

#define B_   4
#define S_   2048
#define H_   8
#define E_   64
#define BH_  (B_ * H_)
#define CS   32                  // rows per chunk (per block)
#define NC   (S_ / CS)           // 64 chunks per (b,h)
#define NBLK (BH_ * NC)          // 2048 blocks
#define RPWV 8                   // rows per wave in K2 downsweep (CS / 4 waves)

// ---------------- K1: scores + chunk partials ----------------
__global__ __launch_bounds__(256) void k_part(const float* __restrict__ keys,
                                              const float* __restrict__ values,
                                              const float* __restrict__ w,
                                              float* __restrict__ e_g,
                                              float* __restrict__ cden,
                                              float* __restrict__ cnum) {
    const int blk = blockIdx.x;
    const int bh  = blk / NC, c = blk % NC;
    const int b   = bh / H_,  h = bh % H_;
    const int t   = threadIdx.x;
    const int wave = t >> 6, lane = t & 63;
    const int cf = lane & 15, rq = lane >> 4;

    __shared__ float e_lds[CS];
    __shared__ float red[16][E_];        // row-group partials, 4KB

    const size_t row0 = (size_t)b * S_ + (size_t)c * CS;

    // scores: wave w covers rows w*8 .. w*8+7 (2 passes of 4 rows)
    const float4 w4 = reinterpret_cast<const float4*>(w)[cf];
    const float* kb = keys + (row0 * H_ + h) * (size_t)E_;
    #pragma unroll
    for (int g = 0; g < 2; ++g) {
        const int r = wave * 8 + g * 4 + rq;
        const float4 kv = *reinterpret_cast<const float4*>(
            kb + (size_t)r * (H_ * E_) + cf * 4);
        float p = kv.x * w4.x + kv.y * w4.y + kv.z * w4.z + kv.w * w4.w;
        p += __shfl_xor(p, 1);
        p += __shfl_xor(p, 2);
        p += __shfl_xor(p, 4);
        p += __shfl_xor(p, 8);
        if (cf == 0) e_lds[r] = __expf(-p * 0.125f);
    }
    __syncthreads();

    // values as float4: lane pattern (rg = t>>4 row-group, c4 = t&15 col4)
    const int c4 = t & 15, rg = t >> 4;
    const float4* vb = reinterpret_cast<const float4*>(
        values + (row0 * H_ + h) * (size_t)E_) + c4;
    float4 acc = make_float4(0.f, 0.f, 0.f, 0.f);
    #pragma unroll
    for (int g = 0; g < CS / 16; ++g) {             // 2 rows per thread
        const int r = g * 16 + rg;
        const float4 v4 = vb[(size_t)r * (H_ * E_ / 4)];
        const float e = e_lds[r];
        acc.x = fmaf(e, v4.x, acc.x);
        acc.y = fmaf(e, v4.y, acc.y);
        acc.z = fmaf(e, v4.z, acc.z);
        acc.w = fmaf(e, v4.w, acc.w);
    }
    *reinterpret_cast<float4*>(&red[rg][c4 * 4]) = acc;

    // den: butterfly over the 32 e values (wave 0)
    if (wave == 0) {
        float d = (lane < CS) ? e_lds[lane] : 0.f;
        d += __shfl_xor(d, 1);
        d += __shfl_xor(d, 2);
        d += __shfl_xor(d, 4);
        d += __shfl_xor(d, 8);
        d += __shfl_xor(d, 16);
        if (lane == 0) cden[blk] = d;
    }
    __syncthreads();

    if (t < E_) {                                   // channel-wise reduce over 16 rg
        float s = 0.f;
        #pragma unroll
        for (int r2 = 0; r2 < 16; ++r2) s += red[r2][t];
        cnum[(size_t)blk * E_ + t] = s;
    }
    if (t < CS) e_g[(size_t)blk * CS + t] = e_lds[t];
}

// ---------------- K2: prefix + downsweep + out ----------------
__global__ __launch_bounds__(256) void k_scan(const float* __restrict__ values,
                                              const float* __restrict__ e_g,
                                              const float* __restrict__ cden,
                                              const float* __restrict__ cnum,
                                              float* __restrict__ out) {
    const int blk = blockIdx.x;
    const int bh  = blk / NC, c = blk % NC;
    const int b   = bh / H_,  h = bh % H_;
    const int t   = threadIdx.x;
    const int wave = t >> 6, lane = t & 63;

    __shared__ float e_lds[CS];
    __shared__ float pnum4[4][E_];
    __shared__ float wnum[4][E_];
    __shared__ float pd4[4], wd[4];

    if (t < CS) e_lds[t] = e_g[(size_t)blk * CS + t];
    __syncthreads();

    // cross-chunk exclusive prefix, wave-strided over predecessors
    const int base = bh * NC;
    float pn = 0.f, pdl = 0.f;
    for (int cp = wave; cp < c; cp += 4) {
        pn  += cnum[(size_t)(base + cp) * E_ + lane];   // 256B coalesced, cache-hot
        pdl += cden[base + cp];                         // uniform
    }
    pnum4[wave][lane] = pn;
    if (lane == 0) pd4[wave] = pdl;

    // in-chunk per-wave partials: wave w owns rows w*8 .. w*8+7
    const size_t row0 = (size_t)b * S_ + (size_t)c * CS;
    const float* vp = values + ((row0 + wave * RPWV) * H_ + h) * (size_t)E_ + lane;
    float v_r[RPWV];
    #pragma unroll
    for (int j = 0; j < RPWV; ++j) v_r[j] = vp[(size_t)j * (H_ * E_)];

    float num = 0.f, den = 0.f;
    #pragma unroll
    for (int j = 0; j < RPWV; ++j) {
        const float e = e_lds[wave * RPWV + j];
        num = fmaf(e, v_r[j], num);
        den += e;
    }
    wnum[wave][lane] = num;
    if (lane == 0) wd[wave] = den;
    __syncthreads();

    float pnum = pnum4[0][lane] + pnum4[1][lane] + pnum4[2][lane] + pnum4[3][lane];
    float pden = pd4[0] + pd4[1] + pd4[2] + pd4[3];
    #pragma unroll
    for (int w2 = 0; w2 < 3; ++w2) {
        if (w2 < wave) { pnum += wnum[w2][lane]; pden += wd[w2]; }
    }

    float* op = out + ((row0 + wave * RPWV) * H_ + h) * (size_t)E_ + lane;  // L==S
    #pragma unroll
    for (int j = 0; j < RPWV; ++j) {
        const float e = e_lds[wave * RPWV + j];
        pnum = fmaf(e, v_r[j], pnum);
        pden += e;
        __builtin_nontemporal_store(pnum * __builtin_amdgcn_rcpf(pden),
                                    &op[(size_t)j * (H_ * E_)]);
    }
}

extern "C" void kernel_launch(void* const* d_in, const int* in_sizes, int n_in,
                              void* d_out, int out_size, void* d_ws, size_t ws_size,
                              hipStream_t stream) {
    // inputs: 0=queries (UNUSED), 1=keys, 2=values, 3=w_score,
    //         4=b_score (cancels), 5=attn_mask (sentinel -> causal)
    const float* keys   = (const float*)d_in[1];
    const float* values = (const float*)d_in[2];
    const float* w      = (const float*)d_in[3];
    float* out = (float*)d_out;

    // workspace (floats): e_g[NBLK*CS] | cnum[NBLK*E] | cden[NBLK]
    float* e_g  = (float*)d_ws;
    float* cnum = e_g + (size_t)NBLK * CS;
    float* cden = cnum + (size_t)NBLK * E_;

    hipLaunchKernelGGL(k_part, dim3(NBLK), dim3(256), 0, stream,
                       keys, values, w, e_g, cden, cnum);
    hipLaunchKernelGGL(k_scan, dim3(NBLK), dim3(256), 0, stream,
                       values, e_g, cden, cnum, out);
}